// Round 4
// baseline (276.760 us; speedup 1.0000x reference)
//
#include <hip/hip_runtime.h>
#include <hip/hip_bf16.h>

// Problem constants
#define NB   8
#define CCH  64
#define CR8  8
#define NPX  2304           // 48*48
#define BCN  (NB*CCH*NPX)   // 1179648
#define LOG2E 1.4426950408889634f

typedef short  short8   __attribute__((ext_vector_type(8)));
typedef unsigned short ushort4t __attribute__((ext_vector_type(4)));
typedef unsigned short ushort8t __attribute__((ext_vector_type(8)));
typedef float  float16t __attribute__((ext_vector_type(16)));

// Workspace layout (float offsets), total 2,469,888 floats = 9.88 MB
// qb/kb: bf16 [b][i][16] rows (c=0..7 data, 8..15 zero) -> MFMA K=16 operands
#define WS_QB1 0
#define WS_KB1 (WS_QB1 + 147456)
#define WS_QB2 (WS_KB1 + 147456)
#define WS_KB2 (WS_QB2 + 147456)
#define WS_V1  (WS_KB2 + 147456)        // bf16 [b][c][i], BCN elems = 589824 floats
#define WS_V2  (WS_V1 + BCN/2)
#define WS_PD  (WS_V2 + BCN/2)          // partial denom [a][b][jsb=18][i] fp32
#define WS_RD  (WS_PD + 2*NB*18*NPX)    // 1/denom [a][b][i]

// ---------------------------------------------------------------------------
// Kernel 1: projections, register-resident x, scalar-cached W, zero LDS.
// grid (36,8) block 256. Wave g: s=g>>1 (stream), og=g&1 (oc-half).
// og half owns: qk ocs og*8..og*8+7 (q if og==0 else k) + v ocs og*32..+31.
// q pre-scaled by log2e. qb/kb rows zero-padded to 16.
// ---------------------------------------------------------------------------
__global__ __launch_bounds__(256) void proj_kernel(
    const float* __restrict__ x1, const float* __restrict__ x2,
    const float* __restrict__ Wqk1, const float* __restrict__ bqk1,
    const float* __restrict__ Wqk2, const float* __restrict__ bqk2,
    const float* __restrict__ Wv1,  const float* __restrict__ bv1,
    const float* __restrict__ Wv2,  const float* __restrict__ bv2,
    float* __restrict__ ws)
{
    const int t  = threadIdx.x;
    const int p  = t & 63;
    const int g  = t >> 6;          // wave id
    const int s  = g >> 1;          // stream
    const int og = g & 1;           // oc half
    const int b  = blockIdx.y;
    const int i  = blockIdx.x * 64 + p;   // pixel

    const float* x   = s ? x2 : x1;
    const float* Wqk = s ? Wqk2 : Wqk1;
    const float* bqk = s ? bqk2 : bqk1;
    const float* Wv  = s ? Wv2  : Wv1;
    const float* bv  = s ? bv2  : bv1;
    unsigned short* qb = (unsigned short*)(ws + (s ? WS_QB2 : WS_QB1));
    unsigned short* kb = (unsigned short*)(ws + (s ? WS_KB2 : WS_KB1));
    unsigned short* v  = (unsigned short*)(ws + (s ? WS_V2  : WS_V1));

    float aqk[8], av[32];
    #pragma unroll
    for (int e = 0; e < 8;  e++) aqk[e] = bqk[og * 8 + e];
    #pragma unroll
    for (int e = 0; e < 32; e++) av[e]  = bv[og * 32 + e];

    const float* xb = x + ((size_t)b * CCH) * NPX + i;
    for (int cc = 0; cc < 64; cc += 16) {
        float xr[16];
        #pragma unroll
        for (int e = 0; e < 16; e++) xr[e] = xb[(cc + e) * NPX];
        #pragma unroll
        for (int e = 0; e < 16; e++) {
            const int c = cc + e;
            #pragma unroll
            for (int r = 0; r < 8; r++)
                aqk[r] = fmaf(Wqk[(og * 8 + r) * 64 + c], xr[e], aqk[r]);
            #pragma unroll
            for (int r = 0; r < 32; r++)
                av[r] = fmaf(Wv[(og * 32 + r) * 64 + c], xr[e], av[r]);
        }
    }

    // qk store: bf16 row [i][0..7] + zero pad [8..15]
    {
        unsigned short* dst = og ? kb : qb;
        const float sc = og ? 1.0f : LOG2E;
        ushort8t vals, zer;
        #pragma unroll
        for (int e = 0; e < 8; e++) {
            __hip_bfloat16 hb = __float2bfloat16(aqk[e] * sc);
            vals[e] = *(unsigned short*)&hb;
            zer[e] = 0;
        }
        const size_t base = (size_t)(b * NPX + i) * 16;
        *(ushort8t*)(dst + base)     = vals;
        *(ushort8t*)(dst + base + 8) = zer;
    }
    // v store: [b][oc][i]
    #pragma unroll
    for (int r = 0; r < 32; r++) {
        __hip_bfloat16 hb = __float2bfloat16(av[r]);
        v[((size_t)b * CCH + og * 32 + r) * NPX + i] = *(unsigned short*)&hb;
    }
}

// ---------------------------------------------------------------------------
// Kernel 2: softmax denominators via MFMA. grid (18 jsb, 16 ab), block 256.
// Wave w owns j-block jsb*128 + w*32 (rows of S^T, A=k). Loop i-blocks of 32
// (B=q). C cols = i, rows = j; per-lane sum of 16 regs + shfl_xor(32) = 32 j.
// 4-wave LDS reduce -> pd[a][b][jsb][i].  No max pass (|S*log2e| < ~50).
// ---------------------------------------------------------------------------
__global__ __launch_bounds__(256) void stats_kernel(float* __restrict__ ws)
{
    const int t  = threadIdx.x;
    const int w  = t >> 6;
    const int n  = t & 31;
    const int h  = (t & 63) >> 5;
    const int jsb = blockIdx.x;     // 0..17
    const int ab  = blockIdx.y;     // a*8+b
    const int b   = ab & 7;
    const int a   = ab >> 3;

    const unsigned short* qb = (const unsigned short*)(ws + (a ? WS_QB2 : WS_QB1));
    const unsigned short* kb = (const unsigned short*)(ws + (a ? WS_KB2 : WS_KB1));
    float* pd = ws + WS_PD;

    __shared__ float red[4][32];

    // A-frag (k), fixed: row m = j
    const int j = jsb * 128 + w * 32 + n;
    const short8 kfrag = *(const short8*)(kb + (size_t)(b * NPX + j) * 16 + h * 8);

    for (int ib = 0; ib < 72; ib++) {
        const int i = ib * 32 + n;
        const short8 qfrag = *(const short8*)(qb + (size_t)(b * NPX + i) * 16 + h * 8);
        float16t acc = {};
        acc = __builtin_amdgcn_mfma_f32_32x32x16_bf16(kfrag, qfrag, acc, 0, 0, 0);
        float ssum = 0.f;
        #pragma unroll
        for (int r = 0; r < 16; r++) ssum += exp2f(acc[r]);
        ssum += __shfl_xor(ssum, 32);       // add other h-half (32 j rows total)
        if (h == 0) red[w][n] = ssum;
        __syncthreads();
        if (t < 32)
            pd[((size_t)ab * 18 + jsb) * NPX + ib * 32 + t] =
                red[0][t] + red[1][t] + red[2][t] + red[3][t];
        __syncthreads();
    }
}

// ---------------------------------------------------------------------------
// Kernel 3: merge 18 partials -> reciprocal. grid (144), block 256.
// ---------------------------------------------------------------------------
__global__ __launch_bounds__(256) void stats_merge(float* __restrict__ ws)
{
    const float* pd = ws + WS_PD;
    float* rd = ws + WS_RD;
    const int idx = blockIdx.x * 256 + threadIdx.x;   // [a][b][i] flat
    const int i  = idx % NPX;
    const int ab = idx / NPX;
    float s = 0.f;
    #pragma unroll
    for (int c = 0; c < 18; c++)
        s += pd[((size_t)ab * 18 + c) * NPX + i];
    rd[idx] = 1.0f / s;
}

// ---------------------------------------------------------------------------
// Kernel 4: output, all-MFMA. grid (36 jt, 8 b, 2 o), block 256.
// Per 64-i chunk: S quadrant (M=i,N=j) = one mfma(qfrag,kfrag) — q/k frags
// straight from global; P = exp2(S)*r_i packed bf16 -> pt[j][i] via 4x
// ds_write_b64 (C rows r&3 = consecutive i). PV: D[c][j] quadrant, A=vt[c][i],
// B=pt[j][i]. kfrag hoisted (constant per wave). 2 barriers/chunk.
// ---------------------------------------------------------------------------
__global__ __launch_bounds__(256) void out_kernel(
    const float* __restrict__ x1, const float* __restrict__ x2,
    const float* __restrict__ gamma, const float* __restrict__ beta,
    const float* __restrict__ ws, float* __restrict__ out)
{
    const int t  = threadIdx.x;
    const int jt = blockIdx.x;
    const int b  = blockIdx.y;
    const int o  = blockIdx.z;

    const int a = o ? 0 : 1;        // attn used: o1<-attn2, o2<-attn1
    const unsigned short* qb = (const unsigned short*)(ws + (a ? WS_QB2 : WS_QB1));
    const unsigned short* kb = (const unsigned short*)(ws + (a ? WS_KB2 : WS_KB1));
    const unsigned short* v  = (const unsigned short*)(ws + (o ? WS_V2 : WS_V1));
    const float* x = o ? x2 : x1;
    const float  scale = o ? beta[0] : gamma[0];
    const float* rr = ws + WS_RD + ((size_t)a * NB + b) * NPX;

    __shared__ unsigned short vt[64][72];   // v[c][i]
    __shared__ unsigned short pt[64][72];   // P[j][i]

    const int j0   = jt * 64;
    const int lane = t & 63;
    const int w    = t >> 6;
    const int n    = lane & 31;
    const int h    = lane >> 5;
    const int jh = w & 1, ih = w >> 1;      // S quadrant
    const int cbase = 32 * (w & 1);         // PV quadrant
    const int jbase = 32 * (w >> 1);

    // k B-frag: lane n = j, k-dim = h*8.. ; constant across chunks
    const short8 kfrag = *(const short8*)(kb + (size_t)(b * NPX + j0 + 32 * jh + n) * 16 + h * 8);

    float16t oacc = {};

    for (int it = 0; it < 36; it++) {
        const int i0 = it * 64;
        __syncthreads();                    // prior PV done (vt/pt reusable)

        // stage vt[c][i]: 512 x 16B segments, 2 per thread
        #pragma unroll
        for (int r = 0; r < 2; r++) {
            const int seg = t + r * 256;
            const int c = seg >> 3, s8 = seg & 7;
            *(float4*)&vt[c][s8 * 8] =
                *(const float4*)(v + ((size_t)b * CCH + c) * NPX + i0 + s8 * 8);
        }

        // S quadrant: A-frag q (m = i), acc fresh
        const short8 qfrag = *(const short8*)(qb + (size_t)(b * NPX + i0 + 32 * ih + n) * 16 + h * 8);
        float16t sc = {};
        sc = __builtin_amdgcn_mfma_f32_32x32x16_bf16(qfrag, kfrag, sc, 0, 0, 0);

        // P = exp2(S)*r_i, pack 4 consecutive i per b64 write
        #pragma unroll
        for (int gq = 0; gq < 4; gq++) {
            const int ibl = 32 * ih + 8 * gq + 4 * h;   // local i of reg group
            const float4 rv = *(const float4*)(rr + i0 + ibl);
            ushort4t pk;
            {
                __hip_bfloat16 hb;
                hb = __float2bfloat16(exp2f(sc[gq * 4 + 0]) * rv.x); pk[0] = *(unsigned short*)&hb;
                hb = __float2bfloat16(exp2f(sc[gq * 4 + 1]) * rv.y); pk[1] = *(unsigned short*)&hb;
                hb = __float2bfloat16(exp2f(sc[gq * 4 + 2]) * rv.z); pk[2] = *(unsigned short*)&hb;
                hb = __float2bfloat16(exp2f(sc[gq * 4 + 3]) * rv.w); pk[3] = *(unsigned short*)&hb;
            }
            *(ushort4t*)&pt[32 * jh + n][ibl] = pk;
        }
        __syncthreads();                    // vt + pt ready

        // PV: 4 MFMAs over 64-i chunk for my 32c x 32j quadrant
        #pragma unroll
        for (int kk = 0; kk < 4; kk++) {
            const short8 afrag = *(const short8*)&vt[cbase + n][kk * 16 + h * 8];
            const short8 bfrag = *(const short8*)&pt[jbase + n][kk * 16 + h * 8];
            oacc = __builtin_amdgcn_mfma_f32_32x32x16_bf16(afrag, bfrag, oacc, 0, 0, 0);
        }
    }

    // epilogue: out = scale*acc + x.  C: col=n -> j, row=(r&3)+8*(r>>2)+4h -> c
    const size_t outoff = o ? (size_t)BCN : 0;
    #pragma unroll
    for (int r = 0; r < 16; r++) {
        const int row = (r & 3) + 8 * (r >> 2) + 4 * h;
        const int c = cbase + row;
        const size_t gidx = ((size_t)b * CCH + c) * NPX + j0 + jbase + n;
        out[outoff + gidx] = fmaf(oacc[r], scale, x[gidx]);
    }
}

// ---------------------------------------------------------------------------
extern "C" void kernel_launch(void* const* d_in, const int* in_sizes, int n_in,
                              void* d_out, int out_size, void* d_ws, size_t ws_size,
                              hipStream_t stream)
{
    const float* x1   = (const float*)d_in[0];
    const float* x2   = (const float*)d_in[1];
    const float* Wqk1 = (const float*)d_in[2];
    const float* bqk1 = (const float*)d_in[3];
    const float* Wqk2 = (const float*)d_in[4];
    const float* bqk2 = (const float*)d_in[5];
    const float* Wv1  = (const float*)d_in[6];
    const float* bv1  = (const float*)d_in[7];
    const float* Wv2  = (const float*)d_in[8];
    const float* bv2  = (const float*)d_in[9];
    const float* gamma = (const float*)d_in[10];
    const float* beta  = (const float*)d_in[11];
    float* out = (float*)d_out;
    float* ws  = (float*)d_ws;

    proj_kernel<<<dim3(36, 8), 256, 0, stream>>>(
        x1, x2, Wqk1, bqk1, Wqk2, bqk2, Wv1, bv1, Wv2, bv2, ws);
    stats_kernel<<<dim3(18, 16), 256, 0, stream>>>(ws);
    stats_merge<<<dim3(144), 256, 0, stream>>>(ws);
    out_kernel<<<dim3(36, 8, 2), 256, 0, stream>>>(x1, x2, gamma, beta, ws, out);
}